// Round 2
// baseline (180.647 us; speedup 1.0000x reference)
//
#include <hip/hip_runtime.h>
#include <hip/hip_bf16.h>

#define BB 64
#define SS 128
#define WW 20
#define NW (BB*SS)      // 8192 words
#define VOCAB 256
#define EE 64
#define HH 256
#define K3 (3*HH)       // 768

typedef short bf16x8 __attribute__((ext_vector_type(8)));
typedef float f32x4  __attribute__((ext_vector_type(4)));

__device__ __forceinline__ float bf2f(unsigned short u) {
    union { unsigned int i; float f; } v; v.i = ((unsigned int)u) << 16; return v.f;
}

// s[0..3] += bf16 row chunk at p (4 consecutive bf16, 8B load)
__device__ __forceinline__ void addrow4(float* s, const ushort* p) {
    uint2 u = *(const uint2*)p;
    union { unsigned int i; float f; } a, b, c, d;
    a.i = u.x << 16;          // element 0 (low half)
    b.i = u.x & 0xffff0000u;  // element 1 (high half)
    c.i = u.y << 16;          // element 2
    d.i = u.y & 0xffff0000u;  // element 3
    s[0] += a.f; s[1] += b.f; s[2] += c.f; s[3] += d.f;
}

// ---------------------------------------------------------------------------
// K1: P[tap][v][h] = sum_e emb[v,e] * w_tap[h,e,tau]   (9 taps: 1 + 3 + 5)
// grid 256 blocks (one per vocab v), 256 threads (one per h). f32 in, bf16 out.
// ---------------------------------------------------------------------------
__global__ __launch_bounds__(256) void build_tables(
        const float* __restrict__ emb,
        const float* __restrict__ w1,
        const float* __restrict__ w3,
        const float* __restrict__ w5,
        __hip_bfloat16* __restrict__ P) {
    __shared__ float emb_s[EE];
    const int v = blockIdx.x;
    const int h = threadIdx.x;
    if (h < EE) emb_s[h] = emb[v*EE + h];
    __syncthreads();

    float acc[9];
    #pragma unroll
    for (int i = 0; i < 9; ++i) acc[i] = 0.f;

    const float* w1r = w1 + h*EE;       // [E][1]
    const float* w3r = w3 + h*EE*3;     // [E][3]
    const float* w5r = w5 + h*EE*5;     // [E][5]

    for (int e = 0; e < EE; ++e) {
        float xe = emb_s[e];
        acc[0] += xe * w1r[e];
        #pragma unroll
        for (int tau = 0; tau < 3; ++tau) acc[1+tau] += xe * w3r[e*3+tau];
        #pragma unroll
        for (int tau = 0; tau < 5; ++tau) acc[4+tau] += xe * w5r[e*5+tau];
    }
    #pragma unroll
    for (int tap = 0; tap < 9; ++tap)
        P[(tap*VOCAB + v)*HH + h] = __float2bfloat16(acc[tap]);
}

// ---------------------------------------------------------------------------
// K2: per word, conv-as-table-lookup + bias + relu + maxpool over W=20.
// One block per word; 4 waves; wave w handles positions t = w, w+4, ...
// Lane owns 4 h values (lane*4 .. +3) -> 8B coalesced row-chunk loads.
// taps: 0 = conv1; 1..3 = conv3 (pad 1); 4..8 = conv5 (pad 2)
// ---------------------------------------------------------------------------
__global__ __launch_bounds__(256) void conv_pool(
        const int* __restrict__ chars,
        const ushort* __restrict__ P,
        const float* __restrict__ b1,
        const float* __restrict__ b3,
        const float* __restrict__ b5,
        __hip_bfloat16* __restrict__ outs) {
    __shared__ int ch[WW];
    __shared__ float red[4][K3];
    const int n = blockIdx.x;
    const int tid = threadIdx.x;
    if (tid < WW) ch[tid] = chars[n*WW + tid];
    __syncthreads();

    const int wave = tid >> 6, lane = tid & 63;
    const int h4 = lane * 4;

    float4 bb1 = *(const float4*)(b1 + h4);
    float4 bb3 = *(const float4*)(b3 + h4);
    float4 bb5 = *(const float4*)(b5 + h4);

    float m1[4] = {0,0,0,0}, m3[4] = {0,0,0,0}, m5[4] = {0,0,0,0};

    for (int t = wave; t < WW; t += 4) {
        float s1[4] = {0,0,0,0}, s3[4] = {0,0,0,0}, s5[4] = {0,0,0,0};
        // conv1 tap
        addrow4(s1, P + (0*VOCAB + ch[t])*HH + h4);
        // conv3 taps (pad 1)
        #pragma unroll
        for (int tau = 0; tau < 3; ++tau) {
            int idx = t + tau - 1;
            if (idx >= 0 && idx < WW)
                addrow4(s3, P + ((1+tau)*VOCAB + ch[idx])*HH + h4);
        }
        // conv5 taps (pad 2)
        #pragma unroll
        for (int tau = 0; tau < 5; ++tau) {
            int idx = t + tau - 2;
            if (idx >= 0 && idx < WW)
                addrow4(s5, P + ((4+tau)*VOCAB + ch[idx])*HH + h4);
        }
        m1[0] = fmaxf(m1[0], fmaxf(s1[0] + bb1.x, 0.f));
        m1[1] = fmaxf(m1[1], fmaxf(s1[1] + bb1.y, 0.f));
        m1[2] = fmaxf(m1[2], fmaxf(s1[2] + bb1.z, 0.f));
        m1[3] = fmaxf(m1[3], fmaxf(s1[3] + bb1.w, 0.f));
        m3[0] = fmaxf(m3[0], fmaxf(s3[0] + bb3.x, 0.f));
        m3[1] = fmaxf(m3[1], fmaxf(s3[1] + bb3.y, 0.f));
        m3[2] = fmaxf(m3[2], fmaxf(s3[2] + bb3.z, 0.f));
        m3[3] = fmaxf(m3[3], fmaxf(s3[3] + bb3.w, 0.f));
        m5[0] = fmaxf(m5[0], fmaxf(s5[0] + bb5.x, 0.f));
        m5[1] = fmaxf(m5[1], fmaxf(s5[1] + bb5.y, 0.f));
        m5[2] = fmaxf(m5[2], fmaxf(s5[2] + bb5.z, 0.f));
        m5[3] = fmaxf(m5[3], fmaxf(s5[3] + bb5.w, 0.f));
    }

    *(float4*)&red[wave][0*HH + h4] = make_float4(m1[0], m1[1], m1[2], m1[3]);
    *(float4*)&red[wave][1*HH + h4] = make_float4(m3[0], m3[1], m3[2], m3[3]);
    *(float4*)&red[wave][2*HH + h4] = make_float4(m5[0], m5[1], m5[2], m5[3]);
    __syncthreads();

    #pragma unroll
    for (int r = 0; r < 3; ++r) {
        int j = tid + r*256;
        float v = fmaxf(fmaxf(red[0][j], red[1][j]), fmaxf(red[2][j], red[3][j]));
        outs[n*K3 + j] = __float2bfloat16(v);
    }
}

// ---------------------------------------------------------------------------
// K2b: convert lw [256][768] f32 -> bf16 (re-run every launch; ws is repoisoned)
// ---------------------------------------------------------------------------
__global__ __launch_bounds__(256) void cvt_lw(
        const float* __restrict__ lw, __hip_bfloat16* __restrict__ lwb) {
    int i = (blockIdx.x * 256 + threadIdx.x) * 4;   // 192 blocks cover 196608
    float4 v = *(const float4*)(lw + i);
    lwb[i+0] = __float2bfloat16(v.x);
    lwb[i+1] = __float2bfloat16(v.y);
    lwb[i+2] = __float2bfloat16(v.z);
    lwb[i+3] = __float2bfloat16(v.w);
}

// ---------------------------------------------------------------------------
// K3: out[n][h'] = outs[n][:] . lw[h'][:] + lb[h']   via MFMA 16x16x32 bf16.
// Block: 4 waves stacked in m; wave = 16m x 64n (4 accumulators).
// A[m][k]: m=lane&15, k=quad*8+j.  B[k][n]=lw[n][k]: n=lane&15, k=quad*8+j.
// C/D: col=lane&15, row=quad*4+reg (verified layouts, learn_hip m89/m91).
// ---------------------------------------------------------------------------
__global__ __launch_bounds__(256) void gemm_out(
        const ushort* __restrict__ outs,   // [8192][768] bf16
        const ushort* __restrict__ lwb,    // [256][768] bf16
        const float* __restrict__ lb,
        float* __restrict__ out) {
    const int tid  = threadIdx.x;
    const int wave = tid >> 6, lane = tid & 63;
    const int m0 = blockIdx.x * 64 + wave * 16;
    const int n0 = blockIdx.y * 64;
    const int mrow = lane & 15, quad = lane >> 4;

    f32x4 acc[4];
    #pragma unroll
    for (int nn = 0; nn < 4; ++nn) acc[nn] = (f32x4){0.f, 0.f, 0.f, 0.f};

    const ushort* arow = outs + (size_t)(m0 + mrow) * K3 + quad * 8;
    const ushort* brow = lwb  + (size_t)(n0 + mrow) * K3 + quad * 8;

    for (int k0 = 0; k0 < K3; k0 += 32) {
        bf16x8 a = *(const bf16x8*)(arow + k0);
        #pragma unroll
        for (int nn = 0; nn < 4; ++nn) {
            bf16x8 b = *(const bf16x8*)(brow + nn*16*K3 + k0);
            acc[nn] = __builtin_amdgcn_mfma_f32_16x16x32_bf16(a, b, acc[nn], 0, 0, 0);
        }
    }

    #pragma unroll
    for (int nn = 0; nn < 4; ++nn) {
        int ncol = n0 + nn*16 + mrow;
        float lbv = lb[ncol];
        #pragma unroll
        for (int r = 0; r < 4; ++r) {
            int m = m0 + quad*4 + r;
            out[(size_t)m*HH + ncol] = acc[nn][r] + lbv;
        }
    }
}

// ---------------------------------------------------------------------------
extern "C" void kernel_launch(void* const* d_in, const int* in_sizes, int n_in,
                              void* d_out, int out_size, void* d_ws, size_t ws_size,
                              hipStream_t stream) {
    const int*   chars = (const int*)d_in[0];
    const float* emb   = (const float*)d_in[1];
    const float* w1    = (const float*)d_in[2];
    const float* b1    = (const float*)d_in[3];
    const float* w3    = (const float*)d_in[4];
    const float* b3    = (const float*)d_in[5];
    const float* w5    = (const float*)d_in[6];
    const float* b5    = (const float*)d_in[7];
    const float* lw    = (const float*)d_in[8];
    const float* lb    = (const float*)d_in[9];

    // workspace layout (bf16): P 9*256*256 (1.18 MB) | outs 8192*768 (12.6 MB) | lwb 256*768 (0.39 MB)
    __hip_bfloat16* P    = (__hip_bfloat16*)d_ws;
    __hip_bfloat16* outs = P + 9 * VOCAB * HH;
    __hip_bfloat16* lwb  = outs + (size_t)NW * K3;

    build_tables<<<VOCAB, 256, 0, stream>>>(emb, w1, w3, w5, P);
    cvt_lw<<<(HH*K3)/1024, 256, 0, stream>>>(lw, lwb);
    conv_pool<<<NW, 256, 0, stream>>>(chars, (const ushort*)P, b1, b3, b5, outs);
    gemm_out<<<dim3(NW/64, HH/64), 256, 0, stream>>>(
        (const ushort*)outs, (const ushort*)lwb, lb, (float*)d_out);
}

// Round 3
// 165.307 us; speedup vs baseline: 1.0928x; 1.0928x over previous
//
#include <hip/hip_runtime.h>
#include <hip/hip_bf16.h>

#define BB 64
#define SS 128
#define WW 20
#define NW (BB*SS)      // 8192 words
#define VOCAB 256
#define EE 64
#define HH 256
#define K3 (3*HH)       // 768
#define NTAP 9          // 1 + 3 + 5

typedef short bf16x8 __attribute__((ext_vector_type(8)));
typedef float f32x4  __attribute__((ext_vector_type(4)));

__device__ __forceinline__ ushort f2bs(float x) {
    __hip_bfloat16 h = __float2bfloat16(x);
    union { __hip_bfloat16 h; ushort u; } c; c.h = h; return c.u;
}

// s[0..3] += bf16 row chunk at p (4 consecutive bf16, 8B load)
__device__ __forceinline__ void addrow4(float* s, const ushort* p) {
    uint2 u = *(const uint2*)p;
    union { unsigned int i; float f; } a, b, c, d;
    a.i = u.x << 16;          // element 0 (low half)
    b.i = u.x & 0xffff0000u;  // element 1 (high half)
    c.i = u.y << 16;          // element 2
    d.i = u.y & 0xffff0000u;  // element 3
    s[0] += a.f; s[1] += b.f; s[2] += c.f; s[3] += d.f;
}

// ---------------------------------------------------------------------------
// K0: transpose weights into wT[tap][e][h] f32 so build_tables reads are
// lane-coalesced in h. taps: 0 = w1(tau0); 1..3 = w3(tau); 4..8 = w5(tau).
// One thread per output element; writes coalesced, scattered reads absorbed
// by L2 (total useful data 590 KB).
// ---------------------------------------------------------------------------
__global__ __launch_bounds__(256) void transpose_w(
        const float* __restrict__ w1,
        const float* __restrict__ w3,
        const float* __restrict__ w5,
        float* __restrict__ wT) {
    int idx = blockIdx.x * 256 + threadIdx.x;     // 9*64*256 = 147456
    int tap = idx >> 14;                          // /16384
    int e   = (idx >> 8) & 63;
    int h   = idx & 255;
    float v;
    if (tap == 0)      v = w1[h*EE + e];
    else if (tap <= 3) v = w3[(h*EE + e)*3 + (tap-1)];
    else               v = w5[(h*EE + e)*5 + (tap-4)];
    wT[idx] = v;
}

// ---------------------------------------------------------------------------
// K1: P[v][tap][h] = sum_e emb[v,e] * wT[tap][e][h]. 2 vocab rows per block.
// All wT reads lane-coalesced. grid 128 blocks x 256 threads (thread = h).
// ---------------------------------------------------------------------------
__global__ __launch_bounds__(256) void build_tables(
        const float* __restrict__ emb,
        const float* __restrict__ wT,
        ushort* __restrict__ P) {
    __shared__ float emb_s[2][EE];
    const int v0 = blockIdx.x * 2;
    const int h  = threadIdx.x;
    if (h < 2*EE) emb_s[h >> 6][h & 63] = emb[v0*EE + h];
    __syncthreads();

    float acc0[NTAP], acc1[NTAP];
    #pragma unroll
    for (int i = 0; i < NTAP; ++i) { acc0[i] = 0.f; acc1[i] = 0.f; }

    #pragma unroll 4
    for (int e = 0; e < EE; ++e) {
        float x0 = emb_s[0][e], x1 = emb_s[1][e];
        #pragma unroll
        for (int tap = 0; tap < NTAP; ++tap) {
            float w = wT[(tap*EE + e)*HH + h];
            acc0[tap] += x0 * w;
            acc1[tap] += x1 * w;
        }
    }
    #pragma unroll
    for (int tap = 0; tap < NTAP; ++tap) {
        P[((v0+0)*NTAP + tap)*HH + h] = f2bs(acc0[tap]);
        P[((v0+1)*NTAP + tap)*HH + h] = f2bs(acc1[tap]);
    }
}

// ---------------------------------------------------------------------------
// K2: conv-as-table-lookup + bias + relu + maxpool. ONE WAVE PER WORD,
// no LDS, no barriers. Chars are wave-uniform -> scalar loads. P layout
// [v][tap][h]: one row-base per char, tap offsets are compile-time byte
// immediates (centered at +HH so offsets span -512..+3584 B, all within
// the 13-bit signed global_load immediate).
// Lane owns h4 = lane*4 .. +3 (8B chunks; 64 lanes cover 256 h).
// ---------------------------------------------------------------------------
__global__ __launch_bounds__(256) void conv_pool(
        const int* __restrict__ chars,
        const ushort* __restrict__ P,     // [VOCAB][NTAP][HH] bf16
        const float* __restrict__ b1,
        const float* __restrict__ b3,
        const float* __restrict__ b5,
        ushort* __restrict__ outs) {      // [NW][K3] bf16
    const int tid  = threadIdx.x;
    const int wave = __builtin_amdgcn_readfirstlane(tid >> 6);
    const int lane = tid & 63;
    const int n    = blockIdx.x * 4 + wave;
    const int h4   = lane * 4;

    // wave-uniform char loads -> SGPRs
    const int* cp = chars + n * WW;
    int c[WW];
    #pragma unroll
    for (int j = 0; j < WW; ++j) c[j] = cp[j];

    // per-char row base (centered at +HH for immediate-offset taps)
    const ushort* rp[WW];
    const ushort* Pc = P + h4 + HH;
    #pragma unroll
    for (int j = 0; j < WW; ++j) rp[j] = Pc + c[j] * (NTAP*HH);

    float4 bb1 = *(const float4*)(b1 + h4);
    float4 bb3 = *(const float4*)(b3 + h4);
    float4 bb5 = *(const float4*)(b5 + h4);

    float m1[4] = {0,0,0,0}, m3[4] = {0,0,0,0}, m5[4] = {0,0,0,0};

    #pragma unroll
    for (int t = 0; t < WW; ++t) {
        float s1[4] = {0,0,0,0}, s3[4] = {0,0,0,0}, s5[4] = {0,0,0,0};
        // conv1: tap 0 at idx t  -> byte offset (0-1)*512
        addrow4(s1, rp[t] - HH);
        // conv3: taps 1..3, idx = t+tau-1
        #pragma unroll
        for (int tau = 0; tau < 3; ++tau) {
            int idx = t + tau - 1;
            if (idx >= 0 && idx < WW)
                addrow4(s3, rp[idx] + tau*HH);          // (1+tau-1)*HH
        }
        // conv5: taps 4..8, idx = t+tau-2
        #pragma unroll
        for (int tau = 0; tau < 5; ++tau) {
            int idx = t + tau - 2;
            if (idx >= 0 && idx < WW)
                addrow4(s5, rp[idx] + (3+tau)*HH);      // (4+tau-1)*HH
        }
        m1[0] = fmaxf(m1[0], s1[0] + bb1.x); m1[1] = fmaxf(m1[1], s1[1] + bb1.y);
        m1[2] = fmaxf(m1[2], s1[2] + bb1.z); m1[3] = fmaxf(m1[3], s1[3] + bb1.w);
        m3[0] = fmaxf(m3[0], s3[0] + bb3.x); m3[1] = fmaxf(m3[1], s3[1] + bb3.y);
        m3[2] = fmaxf(m3[2], s3[2] + bb3.z); m3[3] = fmaxf(m3[3], s3[3] + bb3.w);
        m5[0] = fmaxf(m5[0], s5[0] + bb5.x); m5[1] = fmaxf(m5[1], s5[1] + bb5.y);
        m5[2] = fmaxf(m5[2], s5[2] + bb5.z); m5[3] = fmaxf(m5[3], s5[3] + bb5.w);
    }
    // relu folded into maxpool: max(relu(x)) == max(0, max(x)); m init=0 needs
    // final clamp only if all x<0 -> already handled since m starts at 0? No:
    // m starts 0 and we took max with raw x, so m >= 0 iff clamped. m could be
    // >0 only via x; if all x<0, m=0 == relu result. Correct as-is.

    ushort* op = outs + (size_t)n * K3 + h4;
    ushort4 o;
    o.x = f2bs(m1[0]); o.y = f2bs(m1[1]); o.z = f2bs(m1[2]); o.w = f2bs(m1[3]);
    *(ushort4*)(op + 0*HH) = o;
    o.x = f2bs(m3[0]); o.y = f2bs(m3[1]); o.z = f2bs(m3[2]); o.w = f2bs(m3[3]);
    *(ushort4*)(op + 1*HH) = o;
    o.x = f2bs(m5[0]); o.y = f2bs(m5[1]); o.z = f2bs(m5[2]); o.w = f2bs(m5[3]);
    *(ushort4*)(op + 2*HH) = o;
}

// ---------------------------------------------------------------------------
// K2b: convert lw [256][768] f32 -> bf16
// ---------------------------------------------------------------------------
__global__ __launch_bounds__(256) void cvt_lw(
        const float* __restrict__ lw, ushort* __restrict__ lwb) {
    int i = (blockIdx.x * 256 + threadIdx.x) * 4;   // 192 blocks cover 196608
    float4 v = *(const float4*)(lw + i);
    ushort4 o;
    o.x = f2bs(v.x); o.y = f2bs(v.y); o.z = f2bs(v.z); o.w = f2bs(v.w);
    *(ushort4*)(lwb + i) = o;
}

// ---------------------------------------------------------------------------
// K3: out[n][h'] = outs[n][:] . lw[h'][:] + lb[h']  via MFMA 16x16x32 bf16.
// 4 waves/block stacked in m; wave = 16m x 64n. Explicit double-buffered
// fragment prefetch, fully unrolled K (24 iters) for load/MFMA overlap.
// A[m][k]: m=lane&15, k=quad*8+j. B[k][n]=lw[n][k]: n=lane&15, k=quad*8+j.
// C/D: col=lane&15, row=quad*4+reg (verified, learn_hip m89/m91).
// ---------------------------------------------------------------------------
__global__ __launch_bounds__(256) void gemm_out(
        const ushort* __restrict__ outs,   // [8192][768] bf16
        const ushort* __restrict__ lwb,    // [256][768] bf16
        const float* __restrict__ lb,
        float* __restrict__ out) {
    const int tid  = threadIdx.x;
    const int wave = tid >> 6, lane = tid & 63;
    const int m0 = blockIdx.x * 64 + wave * 16;
    const int n0 = blockIdx.y * 64;
    const int mrow = lane & 15, quad = lane >> 4;

    f32x4 acc[4];
    #pragma unroll
    for (int nn = 0; nn < 4; ++nn) acc[nn] = (f32x4){0.f, 0.f, 0.f, 0.f};

    const ushort* arow = outs + (size_t)(m0 + mrow) * K3 + quad * 8;
    const ushort* brow = lwb  + (size_t)(n0 + mrow) * K3 + quad * 8;

    bf16x8 a_c = *(const bf16x8*)arow;
    bf16x8 b_c[4];
    #pragma unroll
    for (int nn = 0; nn < 4; ++nn) b_c[nn] = *(const bf16x8*)(brow + nn*16*K3);

    #pragma unroll
    for (int it = 0; it < K3/32; ++it) {
        const int kn = (it + 1 < K3/32) ? (it + 1) * 32 : 0;  // wrap: harmless reload
        bf16x8 a_n = *(const bf16x8*)(arow + kn);
        bf16x8 b_n[4];
        #pragma unroll
        for (int nn = 0; nn < 4; ++nn) b_n[nn] = *(const bf16x8*)(brow + nn*16*K3 + kn);
        #pragma unroll
        for (int nn = 0; nn < 4; ++nn)
            acc[nn] = __builtin_amdgcn_mfma_f32_16x16x32_bf16(a_c, b_c[nn], acc[nn], 0, 0, 0);
        a_c = a_n;
        #pragma unroll
        for (int nn = 0; nn < 4; ++nn) b_c[nn] = b_n[nn];
    }

    #pragma unroll
    for (int nn = 0; nn < 4; ++nn) {
        int ncol = n0 + nn*16 + mrow;
        float lbv = lb[ncol];
        #pragma unroll
        for (int r = 0; r < 4; ++r) {
            int m = m0 + quad*4 + r;
            out[(size_t)m*HH + ncol] = acc[nn][r] + lbv;
        }
    }
}

// ---------------------------------------------------------------------------
extern "C" void kernel_launch(void* const* d_in, const int* in_sizes, int n_in,
                              void* d_out, int out_size, void* d_ws, size_t ws_size,
                              hipStream_t stream) {
    const int*   chars = (const int*)d_in[0];
    const float* emb   = (const float*)d_in[1];
    const float* w1    = (const float*)d_in[2];
    const float* b1    = (const float*)d_in[3];
    const float* w3    = (const float*)d_in[4];
    const float* b3    = (const float*)d_in[5];
    const float* w5    = (const float*)d_in[6];
    const float* b5    = (const float*)d_in[7];
    const float* lw    = (const float*)d_in[8];
    const float* lb    = (const float*)d_in[9];

    // ws layout: P [256][9][256] bf16 (1.18MB) | wT [9][64][256] f32 (0.59MB)
    //          | outs [8192][768] bf16 (12.6MB) | lwb [256][768] bf16 (0.39MB)
    ushort* P    = (ushort*)d_ws;
    float*  wT   = (float*)(P + VOCAB * NTAP * HH);
    ushort* outs = (ushort*)(wT + NTAP * EE * HH);
    ushort* lwb  = outs + (size_t)NW * K3;

    transpose_w<<<(NTAP*EE*HH)/256, 256, 0, stream>>>(w1, w3, w5, wT);
    cvt_lw<<<(HH*K3)/1024, 256, 0, stream>>>(lw, lwb);
    build_tables<<<VOCAB/2, 256, 0, stream>>>(emb, wT, P);
    conv_pool<<<NW/4, 256, 0, stream>>>(chars, P, b1, b3, b5, outs);
    gemm_out<<<dim3(NW/64, HH/64), 256, 0, stream>>>(outs, lwb, lb, (float*)d_out);
}

// Round 4
// 150.444 us; speedup vs baseline: 1.2008x; 1.0988x over previous
//
#include <hip/hip_runtime.h>
#include <hip/hip_bf16.h>

#define BB 64
#define SS 128
#define WW 20
#define NW (BB*SS)      // 8192 words
#define VOCAB 256
#define EE 64
#define HH 256
#define K3 (3*HH)       // 768
#define NTAP 9          // 1 + 3 + 5
#define UNIT 2304       // ushorts per vocab unit = 4608 B

typedef short bf16x8 __attribute__((ext_vector_type(8)));
typedef float f32x4  __attribute__((ext_vector_type(4)));

__device__ __forceinline__ ushort f2bs(float x) {
    __hip_bfloat16 h = __float2bfloat16(x);
    union { __hip_bfloat16 h; ushort u; } c; c.h = h; return c.u;
}
__device__ __forceinline__ float blo(unsigned u) {
    union { unsigned i; float f; } c; c.i = u << 16; return c.f;
}
__device__ __forceinline__ float bhi(unsigned u) {
    union { unsigned i; float f; } c; c.i = u & 0xffff0000u; return c.f;
}

#define SET4(d, w0, w1) { d[0]=blo(w0); d[1]=bhi(w0); d[2]=blo(w1); d[3]=bhi(w1); }
#define ADD4(d, w0, w1) { d[0]+=blo(w0); d[1]+=bhi(w0); d[2]+=blo(w1); d[3]+=bhi(w1); }
#define MAX4(m, s) { m[0]=fmaxf(m[0],s[0]); m[1]=fmaxf(m[1],s[1]); \
                     m[2]=fmaxf(m[2],s[2]); m[3]=fmaxf(m[3],s[3]); }

// ---------------------------------------------------------------------------
// P2 layout (per vocab v, 4608 B = 2304 ushorts):
//   chunks 0..3 (1024 B each): [h-group g=h>>2][16 B = taps(2i,2i+1) x 4h bf16]
//   chunk 4 @ byte 4096 (512 B): [g][8 B = tap8 x 4h]
// One char = 5 coalesced wide loads per wave; tap offsets compile-time.
// ---------------------------------------------------------------------------

// K0: transpose weights into wT[tap][e][h] f32 (coalesced reads in K1).
__global__ __launch_bounds__(256) void transpose_w(
        const float* __restrict__ w1,
        const float* __restrict__ w3,
        const float* __restrict__ w5,
        float* __restrict__ wT) {
    int idx = blockIdx.x * 256 + threadIdx.x;     // 9*64*256 = 147456
    int tap = idx >> 14;
    int e   = (idx >> 8) & 63;
    int h   = idx & 255;
    float v;
    if (tap == 0)      v = w1[h*EE + e];
    else if (tap <= 3) v = w3[(h*EE + e)*3 + (tap-1)];
    else               v = w5[(h*EE + e)*5 + (tap-4)];
    wT[idx] = v;
}

// K1: P2 packed table. grid (VOCAB/2, NTAP), 256 threads (thread = h).
__global__ __launch_bounds__(256) void build_tables(
        const float* __restrict__ emb,
        const float* __restrict__ wT,
        ushort* __restrict__ P2) {
    __shared__ float emb_s[2][EE];
    const int v0  = blockIdx.x * 2;
    const int tap = blockIdx.y;
    const int h   = threadIdx.x;
    if (h < 2*EE) emb_s[h >> 6][h & 63] = emb[v0*EE + h];
    __syncthreads();

    float a0 = 0.f, a1 = 0.f;
    const float* wp = wT + (tap*EE)*HH + h;
    #pragma unroll 8
    for (int e = 0; e < EE; ++e) {
        float w = wp[e*HH];
        a0 += emb_s[0][e] * w;
        a1 += emb_s[1][e] * w;
    }
    const int g = h >> 2, r = h & 3;
    const int base = (tap < 8) ? ((tap>>1)*512 + g*8 + (tap&1)*4 + r)
                               : (2048 + g*4 + r);
    P2[(v0+0)*UNIT + base] = f2bs(a0);
    P2[(v0+1)*UNIT + base] = f2bs(a1);
}

// ---------------------------------------------------------------------------
// K2: conv+relu+maxpool via sliding-window over chars. One wave per word.
// Per char: 5 coalesced wide loads; 3-slot (conv3) and 5-slot (conv5)
// rotating accumulators, all indices static after full unroll.
// Bias applied after max: max_t(s_t)+b == max_t(s_t+b). ReLU at the end.
// ---------------------------------------------------------------------------
__global__ __launch_bounds__(256) void conv_pool(
        const int* __restrict__ chars,
        const ushort* __restrict__ P2,
        const float* __restrict__ b1,
        const float* __restrict__ b3,
        const float* __restrict__ b5,
        ushort* __restrict__ outs) {
    const int tid  = threadIdx.x;
    const int wave = tid >> 6, lane = tid & 63;
    const int n    = blockIdx.x * 4 + wave;
    const char* Pb = (const char*)P2;

    const int* cp = chars + n * WW;
    int c[WW];
    #pragma unroll
    for (int j = 0; j < WW; ++j) c[j] = cp[j];   // wave-uniform -> SGPRs

    float acc3[3][4], acc5[5][4], m1[4], m3[4], m5[4];
    #pragma unroll
    for (int i = 0; i < 4; ++i) {
        acc3[0][i] = 0.f; acc5[0][i] = 0.f; acc5[1][i] = 0.f;
        m1[i] = -1e30f; m3[i] = -1e30f; m5[i] = -1e30f;
    }

    uint4 q[2][4]; uint2 e8[2];
    {   // preload char 0
        const char* p = Pb + (size_t)c[0] * 4608;
        #pragma unroll
        for (int i = 0; i < 4; ++i) q[0][i] = *(const uint4*)(p + i*1024 + lane*16);
        e8[0] = *(const uint2*)(p + 4096 + lane*8);
    }

    #pragma unroll
    for (int j = 0; j < WW; ++j) {
        const int cur = j & 1, nxt = cur ^ 1;
        if (j + 1 < WW) {   // prefetch char j+1
            const char* p = Pb + (size_t)c[j+1] * 4608;
            #pragma unroll
            for (int i = 0; i < 4; ++i) q[nxt][i] = *(const uint4*)(p + i*1024 + lane*16);
            e8[nxt] = *(const uint2*)(p + 4096 + lane*8);
        }
        uint4 q0 = q[cur][0], q1 = q[cur][1], q2 = q[cur][2], q3 = q[cur][3];
        uint2 ee = e8[cur];

        // conv1: position j sum is just tap0
        m1[0] = fmaxf(m1[0], blo(q0.x)); m1[1] = fmaxf(m1[1], bhi(q0.x));
        m1[2] = fmaxf(m1[2], blo(q0.y)); m1[3] = fmaxf(m1[3], bhi(q0.y));
        // conv3: char j tap(1+tau) -> position p=j+1-tau
        if (j + 1 < WW) SET4(acc3[(j+1)%3], q0.z, q0.w)   // fresh p=j+1 <- tap1
        ADD4(acc3[j%3], q1.x, q1.y)                        // p=j   <- tap2
        if (j >= 1) { ADD4(acc3[(j-1)%3], q1.z, q1.w)      // p=j-1 <- tap3
                      MAX4(m3, acc3[(j-1)%3]) }            // p=j-1 complete
        // conv5: char j tap(4+tau) -> position p=j+2-tau
        if (j + 2 < WW) SET4(acc5[(j+2)%5], q2.x, q2.y)   // fresh p=j+2 <- tap4
        if (j + 1 < WW) ADD4(acc5[(j+1)%5], q2.z, q2.w)   // p=j+1 <- tap5
        ADD4(acc5[j%5], q3.x, q3.y)                        // p=j   <- tap6
        if (j >= 1) ADD4(acc5[(j-1)%5], q3.z, q3.w)        // p=j-1 <- tap7
        if (j >= 2) { ADD4(acc5[(j-2)%5], ee.x, ee.y)      // p=j-2 <- tap8
                      MAX4(m5, acc5[(j-2)%5]) }            // p=j-2 complete
    }
    MAX4(m3, acc3[(WW-1)%3])                               // p=19
    MAX4(m5, acc5[(WW-2)%5])                               // p=18
    MAX4(m5, acc5[(WW-1)%5])                               // p=19

    const int h4 = lane * 4;
    float4 bb1 = *(const float4*)(b1 + h4);
    float4 bb3 = *(const float4*)(b3 + h4);
    float4 bb5 = *(const float4*)(b5 + h4);
    ushort* op = outs + (size_t)n * K3 + h4;
    ushort4 o;
    o.x = f2bs(fmaxf(m1[0]+bb1.x, 0.f)); o.y = f2bs(fmaxf(m1[1]+bb1.y, 0.f));
    o.z = f2bs(fmaxf(m1[2]+bb1.z, 0.f)); o.w = f2bs(fmaxf(m1[3]+bb1.w, 0.f));
    *(ushort4*)(op + 0*HH) = o;
    o.x = f2bs(fmaxf(m3[0]+bb3.x, 0.f)); o.y = f2bs(fmaxf(m3[1]+bb3.y, 0.f));
    o.z = f2bs(fmaxf(m3[2]+bb3.z, 0.f)); o.w = f2bs(fmaxf(m3[3]+bb3.w, 0.f));
    *(ushort4*)(op + 1*HH) = o;
    o.x = f2bs(fmaxf(m5[0]+bb5.x, 0.f)); o.y = f2bs(fmaxf(m5[1]+bb5.y, 0.f));
    o.z = f2bs(fmaxf(m5[2]+bb5.z, 0.f)); o.w = f2bs(fmaxf(m5[3]+bb5.w, 0.f));
    *(ushort4*)(op + 2*HH) = o;
}

// K2b: convert lw f32 -> bf16
__global__ __launch_bounds__(256) void cvt_lw(
        const float* __restrict__ lw, ushort* __restrict__ lwb) {
    int i = (blockIdx.x * 256 + threadIdx.x) * 4;
    float4 v = *(const float4*)(lw + i);
    ushort4 o;
    o.x = f2bs(v.x); o.y = f2bs(v.y); o.z = f2bs(v.z); o.w = f2bs(v.w);
    *(ushort4*)(lwb + i) = o;
}

// ---------------------------------------------------------------------------
// K3: out = outs @ lw^T + lb via MFMA 16x16x32. Single-wave blocks 16m x 32n,
// grid (512, 8) = 4096 blocks for latency hiding; double-buffered fragments.
// A[m][k]: m=lane&15, k=quad*8+j. B[k][n]=lw[n][k]: n=lane&15, k=quad*8+j.
// C/D: col=lane&15, row=quad*4+reg.
// ---------------------------------------------------------------------------
__global__ __launch_bounds__(64) void gemm_out(
        const ushort* __restrict__ outs,   // [8192][768] bf16
        const ushort* __restrict__ lwb,    // [256][768] bf16
        const float* __restrict__ lb,
        float* __restrict__ out) {
    const int lane = threadIdx.x;
    const int m0 = blockIdx.x * 16;
    const int n0 = blockIdx.y * 32;
    const int mrow = lane & 15, quad = lane >> 4;

    f32x4 acc0 = (f32x4){0.f,0.f,0.f,0.f}, acc1 = (f32x4){0.f,0.f,0.f,0.f};
    const ushort* arow = outs + (size_t)(m0 + mrow) * K3 + quad * 8;
    const ushort* brow = lwb  + (size_t)(n0 + mrow) * K3 + quad * 8;

    bf16x8 a_c  = *(const bf16x8*)arow;
    bf16x8 b_c0 = *(const bf16x8*)brow;
    bf16x8 b_c1 = *(const bf16x8*)(brow + 16*K3);

    #pragma unroll
    for (int it = 0; it < K3/32; ++it) {
        const int kn = (it + 1 < K3/32) ? (it + 1) * 32 : 0;
        bf16x8 a_n  = *(const bf16x8*)(arow + kn);
        bf16x8 b_n0 = *(const bf16x8*)(brow + kn);
        bf16x8 b_n1 = *(const bf16x8*)(brow + 16*K3 + kn);
        acc0 = __builtin_amdgcn_mfma_f32_16x16x32_bf16(a_c, b_c0, acc0, 0, 0, 0);
        acc1 = __builtin_amdgcn_mfma_f32_16x16x32_bf16(a_c, b_c1, acc1, 0, 0, 0);
        a_c = a_n; b_c0 = b_n0; b_c1 = b_n1;
    }

    #pragma unroll
    for (int nn = 0; nn < 2; ++nn) {
        const f32x4 acc = nn ? acc1 : acc0;
        int ncol = n0 + nn*16 + mrow;
        float lbv = lb[ncol];
        #pragma unroll
        for (int r = 0; r < 4; ++r)
            out[(size_t)(m0 + quad*4 + r)*HH + ncol] = acc[r] + lbv;
    }
}

// ---------------------------------------------------------------------------
extern "C" void kernel_launch(void* const* d_in, const int* in_sizes, int n_in,
                              void* d_out, int out_size, void* d_ws, size_t ws_size,
                              hipStream_t stream) {
    const int*   chars = (const int*)d_in[0];
    const float* emb   = (const float*)d_in[1];
    const float* w1    = (const float*)d_in[2];
    const float* b1    = (const float*)d_in[3];
    const float* w3    = (const float*)d_in[4];
    const float* b3    = (const float*)d_in[5];
    const float* w5    = (const float*)d_in[6];
    const float* b5    = (const float*)d_in[7];
    const float* lw    = (const float*)d_in[8];
    const float* lb    = (const float*)d_in[9];

    // ws: P2 [256][2304] bf16 (1.18MB) | wT [9][64][256] f32 (0.59MB)
    //   | outs [8192][768] bf16 (12.6MB) | lwb [256][768] bf16 (0.39MB)
    ushort* P2   = (ushort*)d_ws;
    float*  wT   = (float*)(P2 + VOCAB * UNIT);
    ushort* outs = (ushort*)(wT + NTAP * EE * HH);
    ushort* lwb  = outs + (size_t)NW * K3;

    transpose_w<<<(NTAP*EE*HH)/256, 256, 0, stream>>>(w1, w3, w5, wT);
    cvt_lw<<<(HH*K3)/1024, 256, 0, stream>>>(lw, lwb);
    build_tables<<<dim3(VOCAB/2, NTAP), 256, 0, stream>>>(emb, wT, P2);
    conv_pool<<<NW/4, 256, 0, stream>>>(chars, P2, b1, b3, b5, outs);
    gemm_out<<<dim3(NW/16, HH/32), 64, 0, stream>>>(outs, lwb, lb, (float*)d_out);
}

// Round 5
// 141.512 us; speedup vs baseline: 1.2766x; 1.0631x over previous
//
#include <hip/hip_runtime.h>
#include <hip/hip_bf16.h>

#define BB 64
#define SS 128
#define WW 20
#define NW (BB*SS)      // 8192 words
#define VOCAB 256
#define EE 64
#define HH 256
#define K3 (3*HH)       // 768
#define NTAP 9          // 1 + 3 + 5
#define UNIT 2304       // ushorts per vocab unit = 4608 B

typedef short bf16x8 __attribute__((ext_vector_type(8)));
typedef float f32x4  __attribute__((ext_vector_type(4)));

__device__ __forceinline__ ushort f2bs(float x) {
    __hip_bfloat16 h = __float2bfloat16(x);
    union { __hip_bfloat16 h; ushort u; } c; c.h = h; return c.u;
}
__device__ __forceinline__ float blo(unsigned u) {
    union { unsigned i; float f; } c; c.i = u << 16; return c.f;
}
__device__ __forceinline__ float bhi(unsigned u) {
    union { unsigned i; float f; } c; c.i = u & 0xffff0000u; return c.f;
}

#define SET4(d, w0, w1) { d[0]=blo(w0); d[1]=bhi(w0); d[2]=blo(w1); d[3]=bhi(w1); }
#define ADD4(d, w0, w1) { d[0]+=blo(w0); d[1]+=bhi(w0); d[2]+=blo(w1); d[3]+=bhi(w1); }
#define MAX4(m, s) { m[0]=fmaxf(m[0],s[0]); m[1]=fmaxf(m[1],s[1]); \
                     m[2]=fmaxf(m[2],s[2]); m[3]=fmaxf(m[3],s[3]); }

// ---------------------------------------------------------------------------
// P2 layout (per vocab v, 4608 B = 2304 ushorts):
//   chunks 0..3 (1024 B each): [g=h>>2][16 B = taps(2i,2i+1) x 4h bf16]
//   chunk 4 @ byte 4096 (512 B): [g][8 B = tap8 x 4h]
// j < 2048: chunk=j>>9, w=j&511, g=w>>3, p=w&7 -> tap=2*chunk+(p>>2), h=g*4+(p&3)
// j >= 2048: tap=8, h=j-2048
// ---------------------------------------------------------------------------

// K0: prep. blocks 0..575: wTp[e][j] f32 (column-packed weights, e=idx/2304);
//          blocks 576..767: lw f32 -> bf16.
__global__ __launch_bounds__(256) void prep(
        const float* __restrict__ w1,
        const float* __restrict__ w3,
        const float* __restrict__ w5,
        const float* __restrict__ lw,
        float* __restrict__ wTp,
        ushort* __restrict__ lwb) {
    const int bid = blockIdx.x;
    if (bid < 576) {
        int idx = bid * 256 + threadIdx.x;      // = e*2304 + j, 147456 total
        int e = idx / UNIT;
        int j = idx - e * UNIT;
        int tap, h;
        if (j < 2048) {
            int chunk = j >> 9, w = j & 511, p = w & 7;
            tap = chunk * 2 + (p >> 2);
            h   = (w >> 3) * 4 + (p & 3);
        } else { tap = 8; h = j - 2048; }
        float v;
        if (tap == 0)      v = w1[h*EE + e];
        else if (tap <= 3) v = w3[(h*EE + e)*3 + (tap-1)];
        else               v = w5[(h*EE + e)*5 + (tap-4)];
        wTp[idx] = v;
    } else {
        int i = ((bid - 576) * 256 + threadIdx.x) * 4;
        float4 v = *(const float4*)(lw + i);
        ushort4 o;
        o.x = f2bs(v.x); o.y = f2bs(v.y); o.z = f2bs(v.z); o.w = f2bs(v.w);
        *(ushort4*)(lwb + i) = o;
    }
}

// K1: P2[v][j] = sum_e emb[v][e] * wTp[e][j]. grid (VOCAB/2, 9) x 256 thr.
// Fully coalesced reads (contiguous j per wave) and contiguous writes.
__global__ __launch_bounds__(256) void build_tables(
        const float* __restrict__ emb,
        const float* __restrict__ wTp,
        ushort* __restrict__ P2) {
    __shared__ float emb_s[2][EE];
    const int v0 = blockIdx.x * 2;
    const int j  = blockIdx.y * 256 + threadIdx.x;
    const int t  = threadIdx.x;
    if (t < 2*EE) emb_s[t >> 6][t & 63] = emb[v0*EE + t];
    __syncthreads();

    float a0 = 0.f, a1 = 0.f;
    const float* wp = wTp + j;
    #pragma unroll 8
    for (int e = 0; e < EE; ++e) {
        float w = wp[e * UNIT];
        a0 += emb_s[0][e] * w;
        a1 += emb_s[1][e] * w;
    }
    P2[(size_t)(v0+0)*UNIT + j] = f2bs(a0);
    P2[(size_t)(v0+1)*UNIT + j] = f2bs(a1);
}

// ---------------------------------------------------------------------------
// K2: conv+relu+maxpool, sliding-window. One wave per word; chars forced to
// SGPRs (readfirstlane) so per-char bases are scalar; lane offset = lane*16.
// Per char: 4x dwordx4 + 1x dwordx2 fully-coalesced loads, 1-deep prefetch.
// Bias after max (max(s)+b == max(s+b)); ReLU at the end.
// ---------------------------------------------------------------------------
__global__ __launch_bounds__(256) void conv_pool(
        const int* __restrict__ chars,
        const ushort* __restrict__ P2,
        const float* __restrict__ b1,
        const float* __restrict__ b3,
        const float* __restrict__ b5,
        ushort* __restrict__ outs) {
    const int tid  = threadIdx.x;
    const int wave = tid >> 6, lane = tid & 63;
    const int n    = blockIdx.x * 4 + wave;
    const char* Pb = (const char*)P2;

    const int* cp = chars + n * WW;
    int c[WW];
    #pragma unroll
    for (int j = 0; j < WW; ++j) c[j] = __builtin_amdgcn_readfirstlane(cp[j]);

    float acc3[3][4], acc5[5][4], m1[4], m3[4], m5[4];
    #pragma unroll
    for (int i = 0; i < 4; ++i) {
        acc3[0][i] = 0.f; acc5[0][i] = 0.f; acc5[1][i] = 0.f;
        m1[i] = -1e30f; m3[i] = -1e30f; m5[i] = -1e30f;
    }

    uint4 q[2][4]; uint2 e8[2];
    {
        const char* p = Pb + (size_t)c[0] * 4608;
        #pragma unroll
        for (int i = 0; i < 4; ++i) q[0][i] = *(const uint4*)(p + i*1024 + lane*16);
        e8[0] = *(const uint2*)(p + 4096 + lane*8);
    }

    #pragma unroll
    for (int j = 0; j < WW; ++j) {
        const int cur = j & 1, nxt = cur ^ 1;
        if (j + 1 < WW) {
            const char* p = Pb + (size_t)c[j+1] * 4608;
            #pragma unroll
            for (int i = 0; i < 4; ++i) q[nxt][i] = *(const uint4*)(p + i*1024 + lane*16);
            e8[nxt] = *(const uint2*)(p + 4096 + lane*8);
        }
        uint4 q0 = q[cur][0], q1 = q[cur][1], q2 = q[cur][2], q3 = q[cur][3];
        uint2 ee = e8[cur];

        // conv1: tap0 at position j
        m1[0] = fmaxf(m1[0], blo(q0.x)); m1[1] = fmaxf(m1[1], bhi(q0.x));
        m1[2] = fmaxf(m1[2], blo(q0.y)); m1[3] = fmaxf(m1[3], bhi(q0.y));
        // conv3: char j tap(1+tau) -> position p=j+1-tau
        if (j + 1 < WW) SET4(acc3[(j+1)%3], q0.z, q0.w)
        ADD4(acc3[j%3], q1.x, q1.y)
        if (j >= 1) { ADD4(acc3[(j-1)%3], q1.z, q1.w)
                      MAX4(m3, acc3[(j-1)%3]) }
        // conv5: char j tap(4+tau) -> position p=j+2-tau
        if (j + 2 < WW) SET4(acc5[(j+2)%5], q2.x, q2.y)
        if (j + 1 < WW) ADD4(acc5[(j+1)%5], q2.z, q2.w)
        ADD4(acc5[j%5], q3.x, q3.y)
        if (j >= 1) ADD4(acc5[(j-1)%5], q3.z, q3.w)
        if (j >= 2) { ADD4(acc5[(j-2)%5], ee.x, ee.y)
                      MAX4(m5, acc5[(j-2)%5]) }
    }
    MAX4(m3, acc3[(WW-1)%3])
    MAX4(m5, acc5[(WW-2)%5])
    MAX4(m5, acc5[(WW-1)%5])

    const int h4 = lane * 4;
    float4 bb1 = *(const float4*)(b1 + h4);
    float4 bb3 = *(const float4*)(b3 + h4);
    float4 bb5 = *(const float4*)(b5 + h4);
    ushort* op = outs + (size_t)n * K3 + h4;
    ushort4 o;
    o.x = f2bs(fmaxf(m1[0]+bb1.x, 0.f)); o.y = f2bs(fmaxf(m1[1]+bb1.y, 0.f));
    o.z = f2bs(fmaxf(m1[2]+bb1.z, 0.f)); o.w = f2bs(fmaxf(m1[3]+bb1.w, 0.f));
    *(ushort4*)(op + 0*HH) = o;
    o.x = f2bs(fmaxf(m3[0]+bb3.x, 0.f)); o.y = f2bs(fmaxf(m3[1]+bb3.y, 0.f));
    o.z = f2bs(fmaxf(m3[2]+bb3.z, 0.f)); o.w = f2bs(fmaxf(m3[3]+bb3.w, 0.f));
    *(ushort4*)(op + 1*HH) = o;
    o.x = f2bs(fmaxf(m5[0]+bb5.x, 0.f)); o.y = f2bs(fmaxf(m5[1]+bb5.y, 0.f));
    o.z = f2bs(fmaxf(m5[2]+bb5.z, 0.f)); o.w = f2bs(fmaxf(m5[3]+bb5.w, 0.f));
    *(ushort4*)(op + 2*HH) = o;
}

// ---------------------------------------------------------------------------
// K3: out = outs @ lw^T + lb. 32m x 32n per wave (4 accs), 64-thr blocks,
// grid (256, 8) = 2048 blocks. Double-buffered fragments, fully unrolled K.
// A[m][k]: m=lane&15, k=quad*8+j. B[k][n]=lw[n][k]: n=lane&15, k=quad*8+j.
// C/D: col=lane&15, row=quad*4+reg.
// ---------------------------------------------------------------------------
__global__ __launch_bounds__(64) void gemm_out(
        const ushort* __restrict__ outs,   // [8192][768] bf16
        const ushort* __restrict__ lwb,    // [256][768] bf16
        const float* __restrict__ lb,
        float* __restrict__ out) {
    const int lane = threadIdx.x;
    const int m0 = blockIdx.x * 32;
    const int n0 = blockIdx.y * 32;
    const int mrow = lane & 15, quad = lane >> 4;

    f32x4 acc00 = (f32x4){0,0,0,0}, acc01 = (f32x4){0,0,0,0};
    f32x4 acc10 = (f32x4){0,0,0,0}, acc11 = (f32x4){0,0,0,0};
    const ushort* ap = outs + (size_t)(m0 + mrow) * K3 + quad * 8;
    const ushort* bp = lwb  + (size_t)(n0 + mrow) * K3 + quad * 8;

    bf16x8 a0 = *(const bf16x8*)ap, a1 = *(const bf16x8*)(ap + 16*K3);
    bf16x8 b0 = *(const bf16x8*)bp, b1 = *(const bf16x8*)(bp + 16*K3);

    #pragma unroll
    for (int it = 0; it < K3/32; ++it) {
        const int kn = (it + 1 < K3/32) ? (it + 1) * 32 : 0;
        bf16x8 a0n = *(const bf16x8*)(ap + kn);
        bf16x8 a1n = *(const bf16x8*)(ap + 16*K3 + kn);
        bf16x8 b0n = *(const bf16x8*)(bp + kn);
        bf16x8 b1n = *(const bf16x8*)(bp + 16*K3 + kn);
        acc00 = __builtin_amdgcn_mfma_f32_16x16x32_bf16(a0, b0, acc00, 0, 0, 0);
        acc01 = __builtin_amdgcn_mfma_f32_16x16x32_bf16(a0, b1, acc01, 0, 0, 0);
        acc10 = __builtin_amdgcn_mfma_f32_16x16x32_bf16(a1, b0, acc10, 0, 0, 0);
        acc11 = __builtin_amdgcn_mfma_f32_16x16x32_bf16(a1, b1, acc11, 0, 0, 0);
        a0 = a0n; a1 = a1n; b0 = b0n; b1 = b1n;
    }

    #pragma unroll
    for (int i = 0; i < 2; ++i) {
        #pragma unroll
        for (int jn = 0; jn < 2; ++jn) {
            const f32x4 acc = (i==0) ? (jn==0 ? acc00 : acc01)
                                     : (jn==0 ? acc10 : acc11);
            int ncol = n0 + jn*16 + mrow;
            float lbv = lb[ncol];
            #pragma unroll
            for (int r = 0; r < 4; ++r)
                out[(size_t)(m0 + i*16 + quad*4 + r)*HH + ncol] = acc[r] + lbv;
        }
    }
}

// ---------------------------------------------------------------------------
extern "C" void kernel_launch(void* const* d_in, const int* in_sizes, int n_in,
                              void* d_out, int out_size, void* d_ws, size_t ws_size,
                              hipStream_t stream) {
    const int*   chars = (const int*)d_in[0];
    const float* emb   = (const float*)d_in[1];
    const float* w1    = (const float*)d_in[2];
    const float* b1    = (const float*)d_in[3];
    const float* w3    = (const float*)d_in[4];
    const float* b3    = (const float*)d_in[5];
    const float* w5    = (const float*)d_in[6];
    const float* b5    = (const float*)d_in[7];
    const float* lw    = (const float*)d_in[8];
    const float* lb    = (const float*)d_in[9];

    // ws: P2 [256][2304] bf16 (1.18MB) | wTp [64][2304] f32 (0.59MB)
    //   | outs [8192][768] bf16 (12.6MB) | lwb [256][768] bf16 (0.39MB)
    ushort* P2   = (ushort*)d_ws;
    float*  wTp  = (float*)(P2 + VOCAB * UNIT);
    ushort* outs = (ushort*)(wTp + EE * UNIT);
    ushort* lwb  = outs + (size_t)NW * K3;

    prep<<<768, 256, 0, stream>>>(w1, w3, w5, lw, wTp, lwb);
    build_tables<<<dim3(VOCAB/2, NTAP), 256, 0, stream>>>(emb, wTp, P2);
    conv_pool<<<NW/4, 256, 0, stream>>>(chars, P2, b1, b3, b5, outs);
    gemm_out<<<dim3(NW/32, HH/32), 64, 0, stream>>>(outs, lwb, lb, (float*)d_out);
}